// Round 8
// baseline (44.522 us; speedup 1.0000x reference)
//
#include <hip/hip_runtime.h>
#include <hip/hip_bf16.h>
#include <stdint.h>

#define B_ROWS 8192
#define D_DIM  128
#define NSLAB  16              // column ranges (512 cols each)
#define STEPS  8               // 64-col steps per block

typedef __attribute__((ext_vector_type(8))) __bf16 bf16x8;
typedef __attribute__((ext_vector_type(4))) float  f32x4;

typedef __attribute__((address_space(3))) uint32_t lds_u32;
typedef __attribute__((address_space(1))) const uint32_t glb_u32;

__device__ __forceinline__ float fast_exp2(float x) {
    float r;
    asm("v_exp_f32 %0, %1" : "=v"(r) : "v"(x));
    return r;
}

// ---------------- Kernel 1: l2-normalize rows, cast to bf16 ----------------
__global__ void k_norm(const float* __restrict__ z, __hip_bfloat16* __restrict__ zn) {
    int row  = blockIdx.x * 4 + (threadIdx.x >> 6);
    int lane = threadIdx.x & 63;
    const float2 v = reinterpret_cast<const float2*>(z + (size_t)row * D_DIM)[lane];
    float ss = v.x * v.x + v.y * v.y;
    #pragma unroll
    for (int m = 1; m < 64; m <<= 1) ss += __shfl_xor(ss, m);
    float inv = rsqrtf(fmaxf(ss, 1e-12f));
    __hip_bfloat162 o;
    o.x = __float2bfloat16(v.x * inv);
    o.y = __float2bfloat16(v.y * inv);
    reinterpret_cast<__hip_bfloat162*>(zn + (size_t)row * D_DIM)[lane] = o;
}

// ---------------- Kernel 2: similarity + fused exp row-sums -----------------
// 1024 blocks (4/CU dispatched, ~3 resident -> 12 waves/CU). Block = 4 waves
// (2 row-waves x 2 col-waves) = 128 rows x 64 cols per step, 8 steps.
// A-fragments: global -> registers ONCE (pinned); LDS only stages B
// (16 KB double-buffered, global_load_lds + XOR swizzle, proven R4-R7).
__global__ __launch_bounds__(256, 3) void k_sim(const __bf16* __restrict__ zn,
                                                float* __restrict__ s_partial,
                                                float* __restrict__ pos) {
    __shared__ __align__(16) char  sB[2][16384];
    __shared__ float red[128][2];

    const int tid  = threadIdx.x;
    const int lane = tid & 63;
    const int l15  = lane & 15;
    const int lg   = lane >> 4;          // 0..3
    const int w    = tid >> 6;           // 0..3
    const int wr   = w >> 1;             // 0..1 : rows [wr*64, +64)
    const int wc   = w & 1;              // 0..1 : cols [wc*32, +32)
    const int rt   = blockIdx.x >> 4;    // 0..63   (128-row tile)
    const int cr   = blockIdx.x & 15;    // 0..15   (512-col range)
    const int R0   = rt * 128;
    const int C0   = cr * 512;

    // ---- stage one 64-col B tile (16 KB): 4x 16B per thread, linear LDS
    // dest, inverse-XOR global source (involution on 16B units, row&7)
    auto stage = [&](int gColBase, char* dst) {
        #pragma unroll
        for (int q = 0; q < 4; ++q) {
            int slot = q * 256 + tid;        // 0..1023
            int row  = slot >> 4;            // 0..63
            int u    = slot & 15;
            const __bf16* g = zn + (size_t)(gColBase + row) * D_DIM + ((u ^ (row & 7)) << 3);
            __builtin_amdgcn_global_load_lds((glb_u32*)g, (lds_u32*)(dst + slot * 16), 16, 0, 0);
        }
    };

    stage(C0, sB[0]);                    // first B tile in flight

    // ---- A fragments: global -> registers, held for the whole kernel
    bf16x8 afr[4][4];
    #pragma unroll
    for (int t = 0; t < 4; ++t)
        #pragma unroll
        for (int ks = 0; ks < 4; ++ks) {
            int row = R0 + wr * 64 + t * 16 + l15;
            afr[t][ks] = *reinterpret_cast<const bf16x8*>(
                zn + (size_t)row * D_DIM + ks * 32 + lg * 8);
            // pin: force materialization, forbid remat/reload
            f32x4 tmp = __builtin_bit_cast(f32x4, afr[t][ks]);
            asm volatile("" : "+v"(tmp));
            afr[t][ks] = __builtin_bit_cast(bf16x8, tmp);
        }

    const float C1 = 2.0f * 1.4426950408889634f;   // sim = 2*dot (tau = 0.5)
    const float C0f = -2.0f * 1.4426950408889634f; // exp(sim-2)=exp2(dot*C1+C0f)
    float srow[4][4];
    #pragma unroll
    for (int t = 0; t < 4; ++t)
        #pragma unroll
        for (int r = 0; r < 4; ++r) srow[t][r] = 0.f;

    __syncthreads();                     // B tile 0 landed

    #pragma unroll 1
    for (int s = 0; s < STEPS; ++s) {
        if (s + 1 < STEPS)
            stage(C0 + (s + 1) * 64, sB[(s + 1) & 1]);   // prefetch next

        const char* bb = sB[s & 1];
        bf16x8 bfr[2][4];
        #pragma unroll
        for (int cs = 0; cs < 2; ++cs)
            #pragma unroll
            for (int ks = 0; ks < 4; ++ks) {
                int row = wc * 32 + cs * 16 + l15;
                int kb  = ks * 64 + lg * 16;
                bfr[cs][ks] = *reinterpret_cast<const bf16x8*>(
                    bb + row * 256 + (kb ^ ((row & 7) << 4)));
            }

        #pragma unroll
        for (int t = 0; t < 4; ++t)
            #pragma unroll
            for (int cs = 0; cs < 2; ++cs) {
                f32x4 acc = {0.f, 0.f, 0.f, 0.f};
                #pragma unroll
                for (int ks = 0; ks < 4; ++ks)
                    acc = __builtin_amdgcn_mfma_f32_16x16x32_bf16(afr[t][ks], bfr[cs][ks], acc, 0, 0, 0);

                const int fragRow = R0 + wr * 64 + t * 16;
                const int fragCol = C0 + s * 64 + wc * 32 + cs * 16;
                if (fragRow == fragCol) {        // diagonal frag (wave-uniform)
                    const int col = fragCol + l15;
                    #pragma unroll
                    for (int r = 0; r < 4; ++r) {
                        int row = fragRow + lg * 4 + r;
                        float e = fast_exp2(fmaf(acc[r], C1, C0f));
                        if (col == row) e = 0.f;                         // self
                        if (col == (row ^ 1)) pos[row] = acc[r] * 2.0f;  // partner
                        srow[t][r] += e;
                    }
                } else {
                    #pragma unroll
                    for (int r = 0; r < 4; ++r)
                        srow[t][r] += fast_exp2(fmaf(acc[r], C1, C0f));
                }
            }
        __syncthreads();   // prefetched tile landed; current buffer reusable
    }

    // ---- reduction: 16 lanes sharing a row -> cross-wave (wc) via LDS
    #pragma unroll
    for (int t = 0; t < 4; ++t)
        #pragma unroll
        for (int r = 0; r < 4; ++r) {
            float v = srow[t][r];
            v += __shfl_xor(v, 1);
            v += __shfl_xor(v, 2);
            v += __shfl_xor(v, 4);
            v += __shfl_xor(v, 8);
            if (l15 == 0) red[wr * 64 + t * 16 + lg * 4 + r][wc] = v;
        }
    __syncthreads();
    if (tid < 128)
        s_partial[(size_t)cr * B_ROWS + R0 + tid] = red[tid][0] + red[tid][1];
}

// ---------------- Kernel 3: per-row loss, per-block partial sums ------------
__global__ void k_loss_partial(const float* __restrict__ sp,
                               const float* __restrict__ pos,
                               float* __restrict__ part) {
    int i = blockIdx.x * 256 + threadIdx.x;
    float ssum = 0.f;
    #pragma unroll
    for (int c = 0; c < NSLAB; ++c) ssum += sp[(size_t)c * B_ROWS + i];
    float v = 2.0f + logf(ssum) - pos[i];
    #pragma unroll
    for (int m = 1; m < 64; m <<= 1) v += __shfl_xor(v, m);
    __shared__ float ls[4];
    if ((threadIdx.x & 63) == 0) ls[threadIdx.x >> 6] = v;
    __syncthreads();
    if (threadIdx.x == 0) part[blockIdx.x] = ls[0] + ls[1] + ls[2] + ls[3];
}

// ---------------- Kernel 4: final reduce ------------------------------------
__global__ void k_final(const float* __restrict__ part, float* __restrict__ out) {
    float v = (threadIdx.x < (B_ROWS / 256)) ? part[threadIdx.x] : 0.f;
    #pragma unroll
    for (int m = 1; m < 64; m <<= 1) v += __shfl_xor(v, m);
    if (threadIdx.x == 0) out[0] = v * (1.0f / (float)B_ROWS);
}

extern "C" void kernel_launch(void* const* d_in, const int* in_sizes, int n_in,
                              void* d_out, int out_size, void* d_ws, size_t ws_size,
                              hipStream_t stream) {
    const float* z = (const float*)d_in[0];
    float* out = (float*)d_out;

    char* ws = (char*)d_ws;
    __hip_bfloat16* zn = (__hip_bfloat16*)ws;                              // 2 MB
    float* s_partial = (float*)(ws + (size_t)B_ROWS * D_DIM * 2);          // 512 KB
    float* pos  = (float*)((char*)s_partial + (size_t)NSLAB * B_ROWS * 4); // 32 KB
    float* part = (float*)((char*)pos + (size_t)B_ROWS * 4);               // 128 B

    // 1) normalize + bf16 cast
    k_norm<<<B_ROWS / 4, 256, 0, stream>>>(z, zn);

    // 2) similarity: 64 row-tiles x 16 col-ranges = 1024 blocks, 256 thr
    k_sim<<<64 * NSLAB, 256, 0, stream>>>((const __bf16*)zn, s_partial, pos);

    // 3) per-row loss -> 32 block partials
    k_loss_partial<<<B_ROWS / 256, 256, 0, stream>>>(s_partial, pos, part);

    // 4) final scalar
    k_final<<<1, 64, 0, stream>>>(part, out);
}

// Round 9
// 36.565 us; speedup vs baseline: 1.2176x; 1.2176x over previous
//
#include <hip/hip_runtime.h>
#include <hip/hip_bf16.h>
#include <stdint.h>

#define B_ROWS 8192
#define D_DIM  128
#define NSLAB  8               // column ranges (1024 cols each)
#define STEPS  16              // 64-col steps per block

typedef __attribute__((ext_vector_type(8))) __bf16 bf16x8;
typedef __attribute__((ext_vector_type(4))) float  f32x4;

typedef __attribute__((address_space(3))) uint32_t lds_u32;
typedef __attribute__((address_space(1))) const uint32_t glb_u32;

__device__ __forceinline__ float fast_exp2(float x) {
    float r;
    asm("v_exp_f32 %0, %1" : "=v"(r) : "v"(x));
    return r;
}

// ---------------- Kernel 1: l2-normalize rows, cast to bf16 ----------------
__global__ void k_norm(const float* __restrict__ z, __hip_bfloat16* __restrict__ zn) {
    int row  = blockIdx.x * 4 + (threadIdx.x >> 6);
    int lane = threadIdx.x & 63;
    const float2 v = reinterpret_cast<const float2*>(z + (size_t)row * D_DIM)[lane];
    float ss = v.x * v.x + v.y * v.y;
    #pragma unroll
    for (int m = 1; m < 64; m <<= 1) ss += __shfl_xor(ss, m);
    float inv = rsqrtf(fmaxf(ss, 1e-12f));
    __hip_bfloat162 o;
    o.x = __float2bfloat16(v.x * inv);
    o.y = __float2bfloat16(v.y * inv);
    reinterpret_cast<__hip_bfloat162*>(zn + (size_t)row * D_DIM)[lane] = o;
}

// ---------------- Kernel 2: similarity + fused exp row-sums -----------------
// 512 blocks (2/CU), 512 thr = 8 waves (4 row x 2 col), 16 waves/CU.
// Wave tile: 32 rows x 32 cols per step. A-fragments global->regs (32 VGPR).
// B 64-col tiles double-buffered in LDS (global_load_lds + XOR swizzle,
// validated R4-R8); sync-per-step prefetch (R5's proven pipeline).
__global__ __launch_bounds__(512, 4) void k_sim(const __bf16* __restrict__ zn,
                                                float* __restrict__ s_partial,
                                                float* __restrict__ pos) {
    __shared__ __align__(16) char sB[2][16384];
    __shared__ float red[128][2];

    const int tid  = threadIdx.x;
    const int lane = tid & 63;
    const int l15  = lane & 15;
    const int lg   = lane >> 4;          // 0..3
    const int w    = tid >> 6;           // 0..7
    const int wr   = w >> 1;             // 0..3 : rows [wr*32, +32)
    const int wc   = w & 1;              // 0..1 : cols [wc*32, +32) within step
    const int rt   = blockIdx.x >> 3;    // 0..63   (128-row tile)
    const int cr   = blockIdx.x & 7;     // 0..7    (1024-col range)
    const int R0   = rt * 128;
    const int C0   = cr * 1024;

    // ---- stage one 64-col B tile (16 KB): 2x 16B per thread, linear LDS
    // dest, inverse-XOR global source (involution on 16B units, row&7)
    auto stage = [&](int gColBase, char* dst) {
        #pragma unroll
        for (int q = 0; q < 2; ++q) {
            int slot = q * 512 + tid;        // 0..1023
            int row  = slot >> 4;            // 0..63
            int u    = slot & 15;
            const __bf16* g = zn + (size_t)(gColBase + row) * D_DIM + ((u ^ (row & 7)) << 3);
            __builtin_amdgcn_global_load_lds((glb_u32*)g, (lds_u32*)(dst + slot * 16), 16, 0, 0);
        }
    };

    stage(C0, sB[0]);                    // first B tile in flight

    // ---- A fragments: global -> registers (8 x bf16x8 = 32 VGPR)
    bf16x8 afr[2][4];
    #pragma unroll
    for (int t = 0; t < 2; ++t)
        #pragma unroll
        for (int ks = 0; ks < 4; ++ks) {
            int row = R0 + wr * 32 + t * 16 + l15;
            afr[t][ks] = *reinterpret_cast<const bf16x8*>(
                zn + (size_t)row * D_DIM + ks * 32 + lg * 8);
        }

    const float C1  = 2.0f * 1.4426950408889634f;   // sim = 2*dot (tau = 0.5)
    const float C0f = -2.0f * 1.4426950408889634f;  // exp(sim-2)=exp2(dot*C1+C0f)
    float srow[2][4];
    #pragma unroll
    for (int t = 0; t < 2; ++t)
        #pragma unroll
        for (int r = 0; r < 4; ++r) srow[t][r] = 0.f;

    __syncthreads();                     // B tile 0 landed

    #pragma unroll 1
    for (int s = 0; s < STEPS; ++s) {
        if (s + 1 < STEPS)
            stage(C0 + (s + 1) * 64, sB[(s + 1) & 1]);   // prefetch next

        const char* bb = sB[s & 1];
        bf16x8 bfr[2][4];
        #pragma unroll
        for (int cs = 0; cs < 2; ++cs)
            #pragma unroll
            for (int ks = 0; ks < 4; ++ks) {
                int row = wc * 32 + cs * 16 + l15;
                int kb  = ks * 64 + lg * 16;
                bfr[cs][ks] = *reinterpret_cast<const bf16x8*>(
                    bb + row * 256 + (kb ^ ((row & 7) << 4)));
            }

        #pragma unroll
        for (int t = 0; t < 2; ++t)
            #pragma unroll
            for (int cs = 0; cs < 2; ++cs) {
                f32x4 acc = {0.f, 0.f, 0.f, 0.f};
                #pragma unroll
                for (int ks = 0; ks < 4; ++ks)
                    acc = __builtin_amdgcn_mfma_f32_16x16x32_bf16(afr[t][ks], bfr[cs][ks], acc, 0, 0, 0);

                const int fragRow = R0 + wr * 32 + t * 16;
                const int fragCol = C0 + s * 64 + wc * 32 + cs * 16;
                if (fragRow == fragCol) {        // diagonal frag (wave-uniform)
                    const int col = fragCol + l15;
                    #pragma unroll
                    for (int r = 0; r < 4; ++r) {
                        int row = fragRow + lg * 4 + r;
                        float e = fast_exp2(fmaf(acc[r], C1, C0f));
                        if (col == row) e = 0.f;                         // self
                        if (col == (row ^ 1)) pos[row] = acc[r] * 2.0f;  // partner
                        srow[t][r] += e;
                    }
                } else {
                    #pragma unroll
                    for (int r = 0; r < 4; ++r)
                        srow[t][r] += fast_exp2(fmaf(acc[r], C1, C0f));
                }
            }
        __syncthreads();   // prefetched tile landed; current buffer reusable
    }

    // ---- reduction: 16 lanes sharing a row -> cross-wave (wc) via LDS
    #pragma unroll
    for (int t = 0; t < 2; ++t)
        #pragma unroll
        for (int r = 0; r < 4; ++r) {
            float v = srow[t][r];
            v += __shfl_xor(v, 1);
            v += __shfl_xor(v, 2);
            v += __shfl_xor(v, 4);
            v += __shfl_xor(v, 8);
            if (l15 == 0) red[wr * 32 + t * 16 + lg * 4 + r][wc] = v;
        }
    __syncthreads();
    if (tid < 128)
        s_partial[(size_t)cr * B_ROWS + R0 + tid] = red[tid][0] + red[tid][1];
}

// ---------------- Kernel 3: per-row loss, per-block partial sums ------------
__global__ void k_loss_partial(const float* __restrict__ sp,
                               const float* __restrict__ pos,
                               float* __restrict__ part) {
    int i = blockIdx.x * 256 + threadIdx.x;
    float ssum = 0.f;
    #pragma unroll
    for (int c = 0; c < NSLAB; ++c) ssum += sp[(size_t)c * B_ROWS + i];
    float v = 2.0f + logf(ssum) - pos[i];
    #pragma unroll
    for (int m = 1; m < 64; m <<= 1) v += __shfl_xor(v, m);
    __shared__ float ls[4];
    if ((threadIdx.x & 63) == 0) ls[threadIdx.x >> 6] = v;
    __syncthreads();
    if (threadIdx.x == 0) part[blockIdx.x] = ls[0] + ls[1] + ls[2] + ls[3];
}

// ---------------- Kernel 4: final reduce ------------------------------------
__global__ void k_final(const float* __restrict__ part, float* __restrict__ out) {
    float v = (threadIdx.x < (B_ROWS / 256)) ? part[threadIdx.x] : 0.f;
    #pragma unroll
    for (int m = 1; m < 64; m <<= 1) v += __shfl_xor(v, m);
    if (threadIdx.x == 0) out[0] = v * (1.0f / (float)B_ROWS);
}

extern "C" void kernel_launch(void* const* d_in, const int* in_sizes, int n_in,
                              void* d_out, int out_size, void* d_ws, size_t ws_size,
                              hipStream_t stream) {
    const float* z = (const float*)d_in[0];
    float* out = (float*)d_out;

    char* ws = (char*)d_ws;
    __hip_bfloat16* zn = (__hip_bfloat16*)ws;                              // 2 MB
    float* s_partial = (float*)(ws + (size_t)B_ROWS * D_DIM * 2);          // 256 KB
    float* pos  = (float*)((char*)s_partial + (size_t)NSLAB * B_ROWS * 4); // 32 KB
    float* part = (float*)((char*)pos + (size_t)B_ROWS * 4);               // 128 B

    // 1) normalize + bf16 cast
    k_norm<<<B_ROWS / 4, 256, 0, stream>>>(z, zn);

    // 2) similarity: 64 row-tiles x 8 col-ranges = 512 blocks (2/CU), 512 thr
    k_sim<<<64 * NSLAB, 512, 0, stream>>>((const __bf16*)zn, s_partial, pos);

    // 3) per-row loss -> 32 block partials
    k_loss_partial<<<B_ROWS / 256, 256, 0, stream>>>(s_partial, pos, part);

    // 4) final scalar
    k_final<<<1, 64, 0, stream>>>(part, out);
}